// Round 2
// baseline (417.840 us; speedup 1.0000x reference)
//
#include <hip/hip_runtime.h>
#include <hip/hip_bf16.h>

typedef unsigned short u16;
typedef unsigned int   u32;

#define MM 8192
#define DD 128

using short8 = __attribute__((ext_vector_type(8))) short;
using f32x4  = __attribute__((ext_vector_type(4))) float;

__device__ __forceinline__ u16 f2bf(float f) {
  u32 u = __float_as_uint(f);
  u32 r = u + 0x7fffu + ((u >> 16) & 1u);   // RNE
  return (u16)(r >> 16);
}

// One wave per row: bf16 conversion + squared norms.
__global__ __launch_bounds__(256) void convert_kernel(
    const float* __restrict__ x, const float* __restrict__ y,
    u16* __restrict__ xb, u16* __restrict__ yb,
    float* __restrict__ sqx, float* __restrict__ sqy)
{
  const int wid  = threadIdx.x >> 6;
  const int lane = threadIdx.x & 63;
  const int row  = blockIdx.x * 4 + wid;
  const float2 vx = *(const float2*)(x + (size_t)row * DD + lane * 2);
  const float2 vy = *(const float2*)(y + (size_t)row * DD + lane * 2);
  float sx = vx.x * vx.x + vx.y * vx.y;
  float sy = vy.x * vy.x + vy.y * vy.y;
  #pragma unroll
  for (int off = 1; off < 64; off <<= 1) {
    sx += __shfl_xor(sx, off, 64);
    sy += __shfl_xor(sy, off, 64);
  }
  u32 px = (u32)f2bf(vx.x) | ((u32)f2bf(vx.y) << 16);
  u32 py = (u32)f2bf(vy.x) | ((u32)f2bf(vy.y) << 16);
  *(u32*)(xb + (size_t)row * DD + lane * 2) = px;
  *(u32*)(yb + (size_t)row * DD + lane * 2) = py;
  if (lane == 0) { sqx[row] = sx; sqy[row] = sy; }
}

// 128x128 output tile per block; 4 waves in 2x2, each wave 64x64.
// Row-sum partials accumulate in LDS (ds_add_f32); ONE coalesced global
// atomicAdd per row happens after __syncthreads at kernel end, so the
// main loop's vmcnt queue holds only L2-resident fragment loads.
__global__ __launch_bounds__(256, 4) void hsic_pair_kernel(
    const u16* __restrict__ xb, const u16* __restrict__ yb,
    const float* __restrict__ sqx, const float* __restrict__ sqy,
    float* __restrict__ s, float* __restrict__ t, float* __restrict__ P)
{
  const int i0   = blockIdx.y * 128;
  const int j0   = blockIdx.x * 128;
  const int tid  = threadIdx.x;
  const int wid  = tid >> 6;
  const int lane = tid & 63;
  const int wr   = wid >> 1;
  const int wc   = wid & 1;
  const int g    = lane >> 4;   // 0..3  (K-chunk for A/B frags, row-group for acc)
  const int c    = lane & 15;   // 0..15 (row for A-frag, col for B-frag/acc)

  const int ri = i0 + wr * 64;
  const int cj = j0 + wc * 64;

  __shared__ float lds_s[128];
  __shared__ float lds_t[128];
  __shared__ float red[4];
  if (tid < 128) { lds_s[tid] = 0.f; lds_t[tid] = 0.f; }
  __syncthreads();

  // Persistent B fragments for this wave's 64 columns (x and y).
  short8 bx[4][4], by[4][4];
  float sqxc[4], sqyc[4];
  #pragma unroll
  for (int cs = 0; cs < 4; ++cs) {
    const int crow = cj + cs * 16 + c;     // X/Y row supplying this column
    const u16* pxc = xb + (size_t)crow * DD + g * 8;
    const u16* pyc = yb + (size_t)crow * DD + g * 8;
    #pragma unroll
    for (int kk = 0; kk < 4; ++kk) {
      bx[cs][kk] = *(const short8*)(pxc + kk * 32);
      by[cs][kk] = *(const short8*)(pyc + kk * 32);
    }
    sqxc[cs] = sqx[crow];
    sqyc[cs] = sqy[crow];
  }

  float p_acc = 0.f;

  #pragma unroll
  for (int rs = 0; rs < 4; ++rs) {
    const int arow = ri + rs * 16 + c;     // A-frag row (lane&15)
    const u16* pax = xb + (size_t)arow * DD + g * 8;
    const u16* pay = yb + (size_t)arow * DD + g * 8;
    short8 ax[4], ay[4];
    #pragma unroll
    for (int kk = 0; kk < 4; ++kk) {
      ax[kk] = *(const short8*)(pax + kk * 32);
      ay[kk] = *(const short8*)(pay + kk * 32);
    }
    // acc rows for this lane: ri + rs*16 + g*4 + tt
    float sqxr[4], sqyr[4];
    #pragma unroll
    for (int tt = 0; tt < 4; ++tt) {
      const int rr = ri + rs * 16 + g * 4 + tt;
      sqxr[tt] = sqx[rr];
      sqyr[tt] = sqy[rr];
    }

    float s_acc[4] = {0.f, 0.f, 0.f, 0.f};
    float t_acc[4] = {0.f, 0.f, 0.f, 0.f};

    #pragma unroll
    for (int cs = 0; cs < 4; ++cs) {
      f32x4 accx = {0.f, 0.f, 0.f, 0.f};
      f32x4 accy = {0.f, 0.f, 0.f, 0.f};
      #pragma unroll
      for (int kk = 0; kk < 4; ++kk) {
        accx = __builtin_amdgcn_mfma_f32_16x16x32_bf16(ax[kk], bx[cs][kk], accx, 0, 0, 0);
        accy = __builtin_amdgcn_mfma_f32_16x16x32_bf16(ay[kk], by[cs][kk], accy, 0, 0, 0);
      }
      const int gc = cj + cs * 16 + c;
      #pragma unroll
      for (int tt = 0; tt < 4; ++tt) {
        const int gr = ri + rs * 16 + g * 4 + tt;
        float kx, ly;
        if (gr == gc) {
          kx = 1.f; ly = 1.f;   // exact diagonal
        } else {
          kx = __expf(2.f * accx[tt] - sqxr[tt] - sqxc[cs]);
          ly = __expf(2.f * accy[tt] - sqyr[tt] - sqyc[cs]);
        }
        p_acc    += kx * ly;
        s_acc[tt] += kx;
        t_acc[tt] += ly;
      }
    }

    // Reduce row sums across the 16 lanes sharing g (they hold the 16 cols),
    // then accumulate into LDS partials (cheap ds_add, lgkm queue).
    #pragma unroll
    for (int tt = 0; tt < 4; ++tt) {
      float sv = s_acc[tt];
      float tv = t_acc[tt];
      #pragma unroll
      for (int off = 1; off < 16; off <<= 1) {
        sv += __shfl_xor(sv, off, 64);
        tv += __shfl_xor(tv, off, 64);
      }
      if (c == 0) {
        const int lrow = wr * 64 + rs * 16 + g * 4 + tt;
        atomicAdd(&lds_s[lrow], sv);
        atomicAdd(&lds_t[lrow], tv);
      }
    }
  }

  // Block-reduce P.
  #pragma unroll
  for (int off = 1; off < 64; off <<= 1) p_acc += __shfl_xor(p_acc, off, 64);
  if (lane == 0) red[wid] = p_acc;
  __syncthreads();

  // One coalesced global atomic per row, at the very end (nothing waits on it).
  if (tid < 128) {
    atomicAdd(&s[i0 + tid], lds_s[tid]);
    atomicAdd(&t[i0 + tid], lds_t[tid]);
  }
  if (tid == 0) atomicAdd(P, red[0] + red[1] + red[2] + red[3]);
}

__global__ __launch_bounds__(256) void finalize_kernel(
    const float* __restrict__ s, const float* __restrict__ t,
    const float* __restrict__ P, float* __restrict__ out)
{
  const int tid = threadIdx.x;
  float sk = 0.f, sl = 0.f, cc = 0.f;
  for (int i = tid; i < MM; i += 256) {
    const float a = s[i], b = t[i];
    sk += a; sl += b; cc += a * b;
  }
  #pragma unroll
  for (int off = 1; off < 64; off <<= 1) {
    sk += __shfl_xor(sk, off, 64);
    sl += __shfl_xor(sl, off, 64);
    cc += __shfl_xor(cc, off, 64);
  }
  __shared__ float rs_[4], rl_[4], rc_[4];
  const int wid = tid >> 6, lane = tid & 63;
  if (lane == 0) { rs_[wid] = sk; rl_[wid] = sl; rc_[wid] = cc; }
  __syncthreads();
  if (tid == 0) {
    const double SK = (double)rs_[0] + rs_[1] + rs_[2] + rs_[3];
    const double SL = (double)rl_[0] + rl_[1] + rl_[2] + rl_[3];
    const double C  = (double)rc_[0] + rc_[1] + rc_[2] + rc_[3];
    const double m  = (double)MM;
    const double num = (double)P[0] - (2.0 / m) * C + (SK * SL) / (m * m);
    out[0] = (float)(num / ((m - 1.0) * (m - 1.0)));
  }
}

extern "C" void kernel_launch(void* const* d_in, const int* in_sizes, int n_in,
                              void* d_out, int out_size, void* d_ws, size_t ws_size,
                              hipStream_t stream) {
  const float* x = (const float*)d_in[0];
  const float* y = (const float*)d_in[1];

  char* ws = (char*)d_ws;
  u16*   xb  = (u16*)ws;                                   // 2 MB
  u16*   yb  = (u16*)(ws + (size_t)2 * 1024 * 1024);       // 2 MB
  float* sqx = (float*)(ws + (size_t)4 * 1024 * 1024);     // 32 KB
  float* sqy = sqx + MM;                                   // 32 KB
  float* s   = sqy + MM;                                   // 32 KB
  float* t   = s + MM;                                     // 32 KB
  float* P   = t + MM;                                     // 4 B

  // zero s, t, P (contiguous)
  hipMemsetAsync(s, 0, (size_t)(2 * MM + 1) * sizeof(float), stream);

  convert_kernel<<<MM / 4, 256, 0, stream>>>(x, y, xb, yb, sqx, sqy);

  dim3 grid(MM / 128, MM / 128);
  hsic_pair_kernel<<<grid, 256, 0, stream>>>(xb, yb, sqx, sqy, s, t, P);

  finalize_kernel<<<1, 256, 0, stream>>>(s, t, P, (float*)d_out);
}

// Round 3
// 208.795 us; speedup vs baseline: 2.0012x; 2.0012x over previous
//
#include <hip/hip_runtime.h>
#include <hip/hip_bf16.h>

typedef unsigned short u16;
typedef unsigned int   u32;

#define MM 8192
#define DD 128

using short8 = __attribute__((ext_vector_type(8))) short;
using f32x4  = __attribute__((ext_vector_type(4))) float;

__device__ __forceinline__ u16 f2bf(float f) {
  u32 u = __float_as_uint(f);
  u32 r = u + 0x7fffu + ((u >> 16) & 1u);   // RNE
  return (u16)(r >> 16);
}

// One wave per row: bf16 conversion + squared norms.
__global__ __launch_bounds__(256) void convert_kernel(
    const float* __restrict__ x, const float* __restrict__ y,
    u16* __restrict__ xb, u16* __restrict__ yb,
    float* __restrict__ sqx, float* __restrict__ sqy)
{
  const int wid  = threadIdx.x >> 6;
  const int lane = threadIdx.x & 63;
  const int row  = blockIdx.x * 4 + wid;
  const float2 vx = *(const float2*)(x + (size_t)row * DD + lane * 2);
  const float2 vy = *(const float2*)(y + (size_t)row * DD + lane * 2);
  float sx = vx.x * vx.x + vx.y * vx.y;
  float sy = vy.x * vy.x + vy.y * vy.y;
  #pragma unroll
  for (int off = 1; off < 64; off <<= 1) {
    sx += __shfl_xor(sx, off, 64);
    sy += __shfl_xor(sy, off, 64);
  }
  u32 px = (u32)f2bf(vx.x) | ((u32)f2bf(vx.y) << 16);
  u32 py = (u32)f2bf(vy.x) | ((u32)f2bf(vy.y) << 16);
  *(u32*)(xb + (size_t)row * DD + lane * 2) = px;
  *(u32*)(yb + (size_t)row * DD + lane * 2) = py;
  if (lane == 0) { sqx[row] = sx; sqy[row] = sy; }
}

// 128x128 output tile per block; 4 waves in 2x2, each wave 64x64.
// Row-sum partials accumulate in LDS; one coalesced global atomic per row
// at kernel end. P partial stored per block (no same-address atomic chain).
// launch_bounds(256,2): R1's known-good codegen (VGPR=128, no spill).
__global__ __launch_bounds__(256, 2) void hsic_pair_kernel(
    const u16* __restrict__ xb, const u16* __restrict__ yb,
    const float* __restrict__ sqx, const float* __restrict__ sqy,
    float* __restrict__ s, float* __restrict__ t, float* __restrict__ P_part)
{
  const int i0   = blockIdx.y * 128;
  const int j0   = blockIdx.x * 128;
  const int tid  = threadIdx.x;
  const int wid  = tid >> 6;
  const int lane = tid & 63;
  const int wr   = wid >> 1;
  const int wc   = wid & 1;
  const int g    = lane >> 4;   // 0..3  (K-chunk for A/B frags, row-group for acc)
  const int c    = lane & 15;   // 0..15 (row for A-frag, col for B-frag/acc)

  const int ri = i0 + wr * 64;
  const int cj = j0 + wc * 64;

  __shared__ float lds_s[128];
  __shared__ float lds_t[128];
  __shared__ float red[4];
  if (tid < 128) { lds_s[tid] = 0.f; lds_t[tid] = 0.f; }
  __syncthreads();

  // Persistent-in-source B fragments (compiler rematerializes via L1/L2).
  short8 bx[4][4], by[4][4];
  float sqxc[4], sqyc[4];
  #pragma unroll
  for (int cs = 0; cs < 4; ++cs) {
    const int crow = cj + cs * 16 + c;     // X/Y row supplying this column
    const u16* pxc = xb + (size_t)crow * DD + g * 8;
    const u16* pyc = yb + (size_t)crow * DD + g * 8;
    #pragma unroll
    for (int kk = 0; kk < 4; ++kk) {
      bx[cs][kk] = *(const short8*)(pxc + kk * 32);
      by[cs][kk] = *(const short8*)(pyc + kk * 32);
    }
    sqxc[cs] = sqx[crow];
    sqyc[cs] = sqy[crow];
  }

  float p_acc = 0.f;

  #pragma unroll
  for (int rs = 0; rs < 4; ++rs) {
    const int arow = ri + rs * 16 + c;     // A-frag row (lane&15)
    const u16* pax = xb + (size_t)arow * DD + g * 8;
    const u16* pay = yb + (size_t)arow * DD + g * 8;
    short8 ax[4], ay[4];
    #pragma unroll
    for (int kk = 0; kk < 4; ++kk) {
      ax[kk] = *(const short8*)(pax + kk * 32);
      ay[kk] = *(const short8*)(pay + kk * 32);
    }
    // acc rows for this lane: ri + rs*16 + g*4 + tt
    float sqxr[4], sqyr[4];
    #pragma unroll
    for (int tt = 0; tt < 4; ++tt) {
      const int rr = ri + rs * 16 + g * 4 + tt;
      sqxr[tt] = sqx[rr];
      sqyr[tt] = sqy[rr];
    }

    float s_acc[4] = {0.f, 0.f, 0.f, 0.f};
    float t_acc[4] = {0.f, 0.f, 0.f, 0.f};

    #pragma unroll
    for (int cs = 0; cs < 4; ++cs) {
      f32x4 accx = {0.f, 0.f, 0.f, 0.f};
      f32x4 accy = {0.f, 0.f, 0.f, 0.f};
      #pragma unroll
      for (int kk = 0; kk < 4; ++kk) {
        accx = __builtin_amdgcn_mfma_f32_16x16x32_bf16(ax[kk], bx[cs][kk], accx, 0, 0, 0);
        accy = __builtin_amdgcn_mfma_f32_16x16x32_bf16(ay[kk], by[cs][kk], accy, 0, 0, 0);
      }
      const int gc = cj + cs * 16 + c;
      #pragma unroll
      for (int tt = 0; tt < 4; ++tt) {
        const int gr = ri + rs * 16 + g * 4 + tt;
        float kx, ly;
        if (gr == gc) {
          kx = 1.f; ly = 1.f;   // exact diagonal
        } else {
          kx = __expf(2.f * accx[tt] - sqxr[tt] - sqxc[cs]);
          ly = __expf(2.f * accy[tt] - sqyr[tt] - sqyc[cs]);
        }
        p_acc    += kx * ly;
        s_acc[tt] += kx;
        t_acc[tt] += ly;
      }
    }

    // Reduce row sums across the 16 lanes sharing g (they hold the 16 cols),
    // then accumulate into LDS partials (lgkm queue, cheap).
    #pragma unroll
    for (int tt = 0; tt < 4; ++tt) {
      float sv = s_acc[tt];
      float tv = t_acc[tt];
      #pragma unroll
      for (int off = 1; off < 16; off <<= 1) {
        sv += __shfl_xor(sv, off, 64);
        tv += __shfl_xor(tv, off, 64);
      }
      if (c == 0) {
        const int lrow = wr * 64 + rs * 16 + g * 4 + tt;
        atomicAdd(&lds_s[lrow], sv);
        atomicAdd(&lds_t[lrow], tv);
      }
    }
  }

  // Block-reduce P into a per-block partial (plain store, no contention).
  #pragma unroll
  for (int off = 1; off < 64; off <<= 1) p_acc += __shfl_xor(p_acc, off, 64);
  if (lane == 0) red[wid] = p_acc;
  __syncthreads();

  // One coalesced global atomic per row, at the very end (nothing waits on it).
  if (tid < 128) {
    atomicAdd(&s[i0 + tid], lds_s[tid]);
    atomicAdd(&t[i0 + tid], lds_t[tid]);
  }
  if (tid == 0)
    P_part[blockIdx.y * gridDim.x + blockIdx.x] = red[0] + red[1] + red[2] + red[3];
}

#define NBLK ((MM / 128) * (MM / 128))

__global__ __launch_bounds__(256) void finalize_kernel(
    const float* __restrict__ s, const float* __restrict__ t,
    const float* __restrict__ P_part, float* __restrict__ out)
{
  const int tid = threadIdx.x;
  float sk = 0.f, sl = 0.f, cc = 0.f, pp = 0.f;
  for (int i = tid; i < MM; i += 256) {
    const float a = s[i], b = t[i];
    sk += a; sl += b; cc += a * b;
  }
  for (int i = tid; i < NBLK; i += 256) pp += P_part[i];
  #pragma unroll
  for (int off = 1; off < 64; off <<= 1) {
    sk += __shfl_xor(sk, off, 64);
    sl += __shfl_xor(sl, off, 64);
    cc += __shfl_xor(cc, off, 64);
    pp += __shfl_xor(pp, off, 64);
  }
  __shared__ float rs_[4], rl_[4], rc_[4], rp_[4];
  const int wid = tid >> 6, lane = tid & 63;
  if (lane == 0) { rs_[wid] = sk; rl_[wid] = sl; rc_[wid] = cc; rp_[wid] = pp; }
  __syncthreads();
  if (tid == 0) {
    const double SK = (double)rs_[0] + rs_[1] + rs_[2] + rs_[3];
    const double SL = (double)rl_[0] + rl_[1] + rl_[2] + rl_[3];
    const double C  = (double)rc_[0] + rc_[1] + rc_[2] + rc_[3];
    const double P  = (double)rp_[0] + rp_[1] + rp_[2] + rp_[3];
    const double m  = (double)MM;
    const double num = P - (2.0 / m) * C + (SK * SL) / (m * m);
    out[0] = (float)(num / ((m - 1.0) * (m - 1.0)));
  }
}

extern "C" void kernel_launch(void* const* d_in, const int* in_sizes, int n_in,
                              void* d_out, int out_size, void* d_ws, size_t ws_size,
                              hipStream_t stream) {
  const float* x = (const float*)d_in[0];
  const float* y = (const float*)d_in[1];

  char* ws = (char*)d_ws;
  u16*   xb  = (u16*)ws;                                   // 2 MB
  u16*   yb  = (u16*)(ws + (size_t)2 * 1024 * 1024);       // 2 MB
  float* sqx = (float*)(ws + (size_t)4 * 1024 * 1024);     // 32 KB
  float* sqy = sqx + MM;                                   // 32 KB
  float* s   = sqy + MM;                                   // 32 KB
  float* t   = s + MM;                                     // 32 KB
  float* Pp  = t + MM;                                     // 16 KB (P partials)

  // zero s, t (P_part is written unconditionally by every block)
  hipMemsetAsync(s, 0, (size_t)(2 * MM) * sizeof(float), stream);

  convert_kernel<<<MM / 4, 256, 0, stream>>>(x, y, xb, yb, sqx, sqy);

  dim3 grid(MM / 128, MM / 128);
  hsic_pair_kernel<<<grid, 256, 0, stream>>>(xb, yb, sqx, sqy, s, t, Pp);

  finalize_kernel<<<1, 256, 0, stream>>>(s, t, Pp, (float*)d_out);
}